// Round 1
// baseline (11128.129 us; speedup 1.0000x reference)
//
#include <hip/hip_runtime.h>
#include <math.h>

#define L_ 6
#define H_ 8
#define D_HD 64
#define E_ 512
#define V_ 32000
#define S_ 2048
#define B_ 2
#define M_ (B_*S_)   // 4096 rows

typedef float  floatx4 __attribute__((ext_vector_type(4)));
typedef short  shortx8 __attribute__((ext_vector_type(8)));

__device__ __forceinline__ short f2bf(float f){
  unsigned u = __builtin_bit_cast(unsigned, f);
  u += 0x7FFFu + ((u >> 16) & 1u);   // round-to-nearest-even
  return (short)(u >> 16);
}

__device__ __forceinline__ float gelu_exact(float x){
  return 0.5f * x * (1.0f + erff(x * 0.70710678118654752440f));
}

// ---------------- embedding: x = tok_emb[id]/sqrt(E) + pos_emb[s] ----------
__global__ __launch_bounds__(128) void embed_k(const int* __restrict__ ids,
                                               const float* __restrict__ tok,
                                               const float* __restrict__ pos,
                                               float* __restrict__ x){
  int row = blockIdx.x;            // 0..M_-1  (= b*S + s)
  int s   = row & (S_ - 1);
  int id  = ids[row];
  const float4* te = (const float4*)(tok + (long long)id * E_);
  const float4* pe = (const float4*)(pos + (long long)s  * E_);
  float4 a = te[threadIdx.x];
  float4 b = pe[threadIdx.x];
  const float isq = 0.04419417382415922f;  // 1/sqrt(512)
  float4 o = { a.x*isq + b.x, a.y*isq + b.y, a.z*isq + b.z, a.w*isq + b.w };
  ((float4*)(x + (long long)row * E_))[threadIdx.x] = o;
}

// ---------------- LayerNorm (no bias, eps=1e-6), one block per row ---------
__global__ __launch_bounds__(128) void ln_k(const float* __restrict__ x,
                                            const float* __restrict__ g,
                                            float* __restrict__ out){
  int row = blockIdx.x, tid = threadIdx.x;
  int lane = tid & 63, wid = tid >> 6;
  float4 v = ((const float4*)(x + (long long)row * E_))[tid];
  float s  = v.x + v.y + v.z + v.w;
  float sq = v.x*v.x + v.y*v.y + v.z*v.z + v.w*v.w;
  #pragma unroll
  for(int off = 32; off > 0; off >>= 1){
    s  += __shfl_xor(s,  off, 64);
    sq += __shfl_xor(sq, off, 64);
  }
  __shared__ float ss[2], sqs[2];
  if(lane == 0){ ss[wid] = s; sqs[wid] = sq; }
  __syncthreads();
  s = ss[0] + ss[1]; sq = sqs[0] + sqs[1];
  float mu  = s * (1.0f / E_);
  float var = sq * (1.0f / E_) - mu * mu;
  float rs  = rsqrtf(var + 1e-6f);
  float4 gv = ((const float4*)g)[tid];
  float4 o = { (v.x-mu)*rs*gv.x, (v.y-mu)*rs*gv.y, (v.z-mu)*rs*gv.z, (v.w-mu)*rs*gv.w };
  ((float4*)(out + (long long)row * E_))[tid] = o;
}

// ---------------- generic MFMA GEMM: C = act(A@W + bias) (+res) ------------
// A:[M,K] fp32, W:[K,N] fp32 (row-major), 64x64 tile per 256-thread block.
// act: 0=none, 1=gelu(exact). res added after act.
__global__ __launch_bounds__(256) void gemm_k(const float* __restrict__ A,
                                              const float* __restrict__ W,
                                              const float* __restrict__ bias,
                                              const float* __restrict__ res,
                                              float* __restrict__ C,
                                              int M, int N, int K, int act){
  __shared__ short As[64][40];   // [m][k], pad 32->40 (16B-aligned rows)
  __shared__ short Bs[64][40];   // [n][k] (transposed weight tile)
  int tid  = threadIdx.x;
  long long m0 = (long long)blockIdx.y * 64;
  long long n0 = (long long)blockIdx.x * 64;
  int wave = tid >> 6, lane = tid & 63, quad = lane >> 4, l16 = lane & 15;
  floatx4 acc[4] = {{0,0,0,0},{0,0,0,0},{0,0,0,0},{0,0,0,0}};

  int ar = tid >> 2,  ac  = (tid & 3) * 8;   // A staging: row, col-chunk
  int bk = tid >> 3,  bn8 = (tid & 7) * 8;   // W staging: k-row, n-chunk

  for(int k0 = 0; k0 < K; k0 += 32){
    const float* ap = A + (m0 + ar) * K + k0 + ac;
    float4 a0 = ((const float4*)ap)[0], a1 = ((const float4*)ap)[1];
    shortx8 av;
    av[0]=f2bf(a0.x); av[1]=f2bf(a0.y); av[2]=f2bf(a0.z); av[3]=f2bf(a0.w);
    av[4]=f2bf(a1.x); av[5]=f2bf(a1.y); av[6]=f2bf(a1.z); av[7]=f2bf(a1.w);
    *((shortx8*)&As[ar][ac]) = av;

    const float* bp = W + (long long)(k0 + bk) * N + n0 + bn8;
    float4 b0 = ((const float4*)bp)[0], b1 = ((const float4*)bp)[1];
    Bs[bn8+0][bk]=f2bf(b0.x); Bs[bn8+1][bk]=f2bf(b0.y);
    Bs[bn8+2][bk]=f2bf(b0.z); Bs[bn8+3][bk]=f2bf(b0.w);
    Bs[bn8+4][bk]=f2bf(b1.x); Bs[bn8+5][bk]=f2bf(b1.y);
    Bs[bn8+6][bk]=f2bf(b1.z); Bs[bn8+7][bk]=f2bf(b1.w);
    __syncthreads();

    shortx8 af = *((const shortx8*)&As[16*wave + l16][quad*8]);
    #pragma unroll
    for(int t = 0; t < 4; t++){
      shortx8 bf8 = *((const shortx8*)&Bs[16*t + l16][quad*8]);
      acc[t] = __builtin_amdgcn_mfma_f32_16x16x32_bf16(af, bf8, acc[t], 0, 0, 0);
    }
    __syncthreads();
  }

  #pragma unroll
  for(int t = 0; t < 4; t++){
    #pragma unroll
    for(int r = 0; r < 4; r++){
      long long row = m0 + 16*wave + quad*4 + r;
      long long col = n0 + 16*t + l16;
      float v = acc[t][r];
      if(bias) v += bias[col];
      if(act)  v = gelu_exact(v);
      if(res)  v += res[row * N + col];
      C[row * N + col] = v;
    }
  }
}

// ---------------- attention: per-wave one q row, 4 rows per block ----------
// qkv: [B,S,3E]; out: [B,S,E]. Exact two-pass softmax, scores in LDS.
__global__ __launch_bounds__(256) void attn_k(const float* __restrict__ qkv,
                                              float* __restrict__ out){
  __shared__ float sp[4][S_];    // 32 KB score rows
  __shared__ float qs[4][64];
  int tid = threadIdx.x, wave = tid >> 6, lane = tid & 63;
  int blk = blockIdx.x;                 // 0 .. B*H*S/4-1
  int qb  = blk & (S_/4 - 1);           // 512 q-blocks per (b,h)
  int bh  = blk >> 9;
  int b = bh >> 3, h = bh & 7;
  int q = qb * 4 + wave;

  const float* base = qkv + (long long)b * S_ * (3*E_);
  qs[wave][lane] = base[(long long)q * (3*E_) + h*64 + lane] * 0.125f; // /sqrt(64)
  __syncthreads();

  const float* Kb = base + E_   + h*64;
  const float* Vb = base + 2*E_ + h*64;
  float* sprow = sp[wave];
  const float4* q4 = (const float4*)qs[wave];

  for(int k0 = 0; k0 <= q; k0 += 64){
    int k = k0 + lane;
    if(k <= q){
      const float4* kr = (const float4*)(Kb + (long long)k * (3*E_));
      float acc = 0.f;
      #pragma unroll
      for(int d = 0; d < 16; d++){
        float4 kv = kr[d]; float4 qv = q4[d];
        acc += qv.x*kv.x + qv.y*kv.y + qv.z*kv.z + qv.w*kv.w;
      }
      sprow[k] = acc;
    }
  }
  float m = -1e30f;
  for(int i = lane; i <= q; i += 64) m = fmaxf(m, sprow[i]);
  #pragma unroll
  for(int off = 32; off > 0; off >>= 1) m = fmaxf(m, __shfl_xor(m, off, 64));
  float sum = 0.f;
  for(int i = lane; i <= q; i += 64){
    float e = __expf(sprow[i] - m); sprow[i] = e; sum += e;
  }
  #pragma unroll
  for(int off = 32; off > 0; off >>= 1) sum += __shfl_xor(sum, off, 64);
  float inv = 1.0f / sum;

  float acc = 0.f;
  for(int k = 0; k <= q; k++) acc += sprow[k] * Vb[(long long)k * (3*E_) + lane];
  out[((long long)(b*S_ + q)) * E_ + h*64 + lane] = acc * inv;
}

// ---------------------------------------------------------------------------
extern "C" void kernel_launch(void* const* d_in, const int* in_sizes, int n_in,
                              void* d_out, int out_size, void* d_ws, size_t ws_size,
                              hipStream_t stream){
  const int*   ids    = (const int*)d_in[0];
  const float* tok    = (const float*)d_in[1];
  const float* pos    = (const float*)d_in[2];
  const float* qkv_w  = (const float*)d_in[3];
  const float* qkv_b  = (const float*)d_in[4];
  const float* proj_w = (const float*)d_in[5];
  const float* proj_b = (const float*)d_in[6];
  const float* fc1_w  = (const float*)d_in[7];
  const float* fc1_b  = (const float*)d_in[8];
  const float* fc2_w  = (const float*)d_in[9];
  const float* fc2_b  = (const float*)d_in[10];
  const float* ln1_g  = (const float*)d_in[11];
  const float* ln2_g  = (const float*)d_in[12];
  const float* lnf_g  = (const float*)d_in[13];
  const float* out_w  = (const float*)d_in[14];
  float* logits = (float*)d_out;

  char* w = (char*)d_ws;
  float* x   = (float*)(w);                        // [4096,512]   8 MB
  float* h   = (float*)(w + (8ll  << 20));         // [4096,512]   8 MB
  float* qkv = (float*)(w + (16ll << 20));         // [4096,1536] 24 MB
  float* f1  = (float*)(w + (40ll << 20));         // [4096,2048] 32 MB

  embed_k<<<M_, 128, 0, stream>>>(ids, tok, pos, x);

  for(int l = 0; l < L_; l++){
    ln_k<<<M_, 128, 0, stream>>>(x, ln1_g + l*E_, h);
    gemm_k<<<dim3(1536/64, M_/64), 256, 0, stream>>>(
        h, qkv_w + (long long)l*E_*1536, qkv_b + l*1536, nullptr, qkv,
        M_, 1536, E_, 0);
    attn_k<<<(B_*H_*S_)/4, 256, 0, stream>>>(qkv, h);
    gemm_k<<<dim3(512/64, M_/64), 256, 0, stream>>>(
        h, proj_w + (long long)l*E_*E_, proj_b + l*E_, x, x,
        M_, E_, E_, 0);
    ln_k<<<M_, 128, 0, stream>>>(x, ln2_g + l*E_, h);
    gemm_k<<<dim3(2048/64, M_/64), 256, 0, stream>>>(
        h, fc1_w + (long long)l*E_*2048, fc1_b + l*2048, nullptr, f1,
        M_, 2048, E_, 1);
    gemm_k<<<dim3(512/64, M_/64), 256, 0, stream>>>(
        f1, fc2_w + (long long)l*2048*E_, fc2_b + l*E_, x, x,
        M_, E_, 2048, 0);
  }

  ln_k<<<M_, 128, 0, stream>>>(x, lnf_g, h);
  gemm_k<<<dim3(V_/64, M_/64), 256, 0, stream>>>(
      h, out_w, nullptr, nullptr, logits,
      M_, V_, E_, 0);
}